// Round 1
// baseline (217.895 us; speedup 1.0000x reference)
//
#include <hip/hip_runtime.h>
#include <hip/hip_bf16.h>
#include <math.h>

// Fused MLP 256->64->16->4 + global softmax over flattened [B*4].
//
// Layer 1 via bf16 MFMA (16x16x32), 3-term split precision:
//   x*w ~= xh*wh + xl*wh + xh*wl   (xl*wl ~2^-18 dropped; verified R5 7.6e-6)
// R7 changes vs R6 (layouts/math identical):
//  - main loop restructured for register pressure: mt halves processed
//    sequentially with a rolling 2-float4 x prefetch (8+8 regs vs 16+16),
//    and B-fragments streamed per-t from LDS (8 regs vs 32). Live set
//    ~82 VGPR vs ~116+ under the 128-VGPR cap of __launch_bounds__(512,4)
//    -> eliminates scratch spill traffic (~134 MB) in the hot loop.
//  - expf -> __expf in epilogue.
// w1' staged per block in LDS [n][k] bf16 hi+lo, k-stride 520 (260dw%32==4).
// Epilogue reuses w1' LDS as h-stash (stride 68), layer-2/3 2 threads/row.
// exp unnormalized + 1 atomic/block; norm_kernel scales by 1/S.

typedef __attribute__((ext_vector_type(8))) short bf16x8;  // 8 bf16 = 4 VGPRs
typedef __attribute__((ext_vector_type(4))) float f32x4;

#define WK 520
#define HS 68
#define NBLOCKS 512   // 131072 rows / 256 rows per block

__device__ __forceinline__ short f2bf(float v) {   // scalar fallback (staging)
    unsigned u = __float_as_uint(v);
    unsigned r = (u + 0x7FFFu + ((u >> 16) & 1u)) >> 16;
    return (short)r;
}
__device__ __forceinline__ float bf2f(short s) {
    return __uint_as_float(((unsigned)(unsigned short)s) << 16);
}

// 8 fp32 -> bf16 hi + lo fragments, packed converts
__device__ __forceinline__ void cvt8(const float4 v0, const float4 v1,
                                     bf16x8& ah, bf16x8& al)
{
    const float f[8] = {v0.x, v0.y, v0.z, v0.w, v1.x, v1.y, v1.z, v1.w};
    unsigned* ahp = (unsigned*)&ah;
    unsigned* alp = (unsigned*)&al;
#pragma unroll
    for (int p = 0; p < 4; ++p) {
        float2 fp = make_float2(f[2 * p], f[2 * p + 1]);
        __hip_bfloat162 h2 = __float22bfloat162_rn(fp);      // v_cvt_pk_bf16_f32
        float2 hf = __bfloat1622float2(h2);
        __hip_bfloat162 l2 =
            __float22bfloat162_rn(make_float2(fp.x - hf.x, fp.y - hf.y));
        union { __hip_bfloat162 b; unsigned u; } ch, cl;
        ch.b = h2; cl.b = l2;
        ahp[p] = ch.u;
        alp[p] = cl.u;
    }
}

__global__ __launch_bounds__(512, 4)
void mlp_kernel(const float* __restrict__ x, const float* __restrict__ w1,
                const float* __restrict__ b1, const float* __restrict__ w2,
                const float* __restrict__ b2, const float* __restrict__ w3,
                const float* __restrict__ b3, float* __restrict__ out,
                float* __restrict__ wsum)
{
    // union: wlds = 64*520*2 = 66560 B; hs = 256*68*4 = 69632 B
    __shared__ __align__(16) char smem[256 * HS * 4];
    __shared__ float ws2[64 * 16];
    __shared__ float ws3[64];
    __shared__ float bs1[64];
    __shared__ float bsum[8];
    short* wlds = (short*)smem;
    float* hs   = (float*)smem;

    const int tid  = threadIdx.x;
    const int lane = tid & 63;
    const int wid  = tid >> 6;    // 0..7
    const int quad = lane >> 4;   // 0..3
    const int m16  = lane & 15;

    // ---- stage small weights + w1 -> bf16 hi/lo in LDS ----
    for (int i = tid; i < 1024; i += 512) ws2[i] = w2[i];
    if (tid < 64) ws3[tid] = w3[tid];
    if (tid >= 64 && tid < 128) bs1[tid - 64] = b1[tid - 64];
    {
        const int n  = tid & 63;
        const int kb = (tid >> 6) * 4;
        for (int kk = kb; kk < 256; kk += 32) {
            const float v0 = w1[(size_t)(kk + 0) * 64 + n];
            const float v1 = w1[(size_t)(kk + 1) * 64 + n];
            const float v2 = w1[(size_t)(kk + 2) * 64 + n];
            const float v3 = w1[(size_t)(kk + 3) * 64 + n];
            short4 hi, lo;
            hi.x = f2bf(v0); lo.x = f2bf(v0 - bf2f(hi.x));
            hi.y = f2bf(v1); lo.y = f2bf(v1 - bf2f(hi.y));
            hi.z = f2bf(v2); lo.z = f2bf(v2 - bf2f(hi.z));
            hi.w = f2bf(v3); lo.w = f2bf(v3 - bf2f(hi.w));
            *(short4*)&wlds[n * WK + kk]       = hi;   // hi at k
            *(short4*)&wlds[n * WK + 256 + kk] = lo;   // lo at 256 + k
        }
    }
    __syncthreads();

    // ---- layer 1 MFMA: wave = 32 rows x 64 cols ----
    const int row0 = blockIdx.x * 256 + wid * 32;
    // per-lane x base: row = row0 + mt*16 + m16, col = s*32 + quad*8
    const float* xb0 = x + (size_t)(row0 + m16) * 256 + quad * 8;
    const float* xb1 = xb0 + 16 * 256;

    f32x4 acc[2][4];
#pragma unroll
    for (int mt = 0; mt < 2; ++mt)
#pragma unroll
        for (int t = 0; t < 4; ++t) acc[mt][t] = (f32x4)0.0f;

    // rolling prefetch: one (s, mt) x-pair in flight (8 regs + 8 in flight)
    float4 c0 = *(const float4*)(xb0);
    float4 c1 = *(const float4*)(xb0 + 4);

#pragma unroll
    for (int s = 0; s < 8; ++s) {
#pragma unroll
        for (int mt = 0; mt < 2; ++mt) {
            float4 n0, n1;
            if (s < 7 || mt == 0) {   // issue next (s,mt) loads FIRST
                const float* nb = (mt == 0) ? (xb1 + s * 32)
                                            : (xb0 + (s + 1) * 32);
                n0 = *(const float4*)nb;
                n1 = *(const float4*)(nb + 4);
            }
            bf16x8 ah, al;
            cvt8(c0, c1, ah, al);
            // 3-term split: ah*bh + al*bh + ah*bl, B-frags streamed per t
#pragma unroll
            for (int t = 0; t < 4; ++t) {
                const short* bp =
                    &wlds[(t * 16 + m16) * WK + s * 32 + quad * 8];
                const bf16x8 bh = *(const bf16x8*)bp;
                const bf16x8 bl = *(const bf16x8*)(bp + 256);
                acc[mt][t] = __builtin_amdgcn_mfma_f32_16x16x32_bf16(
                    ah, bh, acc[mt][t], 0, 0, 0);
                acc[mt][t] = __builtin_amdgcn_mfma_f32_16x16x32_bf16(
                    al, bh, acc[mt][t], 0, 0, 0);
                acc[mt][t] = __builtin_amdgcn_mfma_f32_16x16x32_bf16(
                    ah, bl, acc[mt][t], 0, 0, 0);
            }
            if (s < 7 || mt == 0) { c0 = n0; c1 = n1; }
        }
    }
    __syncthreads();   // all waves done reading wlds -> reuse as hs

    // ---- bias + relu -> h stash (C/D: col = t*16+m16, row = quad*4+r) ----
#pragma unroll
    for (int mt = 0; mt < 2; ++mt)
#pragma unroll
        for (int t = 0; t < 4; ++t) {
            const float bc = bs1[t * 16 + m16];
#pragma unroll
            for (int r = 0; r < 4; ++r) {
                const int rr = wid * 32 + mt * 16 + quad * 4 + r;
                hs[rr * HS + t * 16 + m16] = fmaxf(acc[mt][t][r] + bc, 0.0f);
            }
        }
    __syncthreads();

    // ---- layers 2/3: 2 threads per row, 8 z2-cols each ----
    const int r2 = tid >> 1;
    const int jq = (tid & 1) * 8;
    float z2[8];
#pragma unroll
    for (int jj = 0; jj < 8; ++jj) z2[jj] = b2[jq + jj];
#pragma unroll 4
    for (int c = 0; c < 64; c += 4) {
        const float4 h4 = *(const float4*)&hs[r2 * HS + c];
        const float hv[4] = {h4.x, h4.y, h4.z, h4.w};
#pragma unroll
        for (int i = 0; i < 4; ++i)
#pragma unroll
            for (int jj = 0; jj < 8; ++jj)
                z2[jj] = fmaf(hv[i], ws2[(c + i) * 16 + jq + jj], z2[jj]);
    }
    float l0 = 0.f, l1 = 0.f, l2 = 0.f, l3 = 0.f;
#pragma unroll
    for (int jj = 0; jj < 8; ++jj) {
        const float th = tanhf(z2[jj]);
        const int j = jq + jj;
        l0 = fmaf(th, ws3[j * 4 + 0], l0);
        l1 = fmaf(th, ws3[j * 4 + 1], l1);
        l2 = fmaf(th, ws3[j * 4 + 2], l2);
        l3 = fmaf(th, ws3[j * 4 + 3], l3);
    }
    l0 += __shfl_xor(l0, 1); l1 += __shfl_xor(l1, 1);
    l2 += __shfl_xor(l2, 1); l3 += __shfl_xor(l3, 1);

    float s = 0.0f;
    if ((tid & 1) == 0) {
        const float e0 = __expf(l0 + b3[0]);
        const float e1 = __expf(l1 + b3[1]);
        const float e2 = __expf(l2 + b3[2]);
        const float e3 = __expf(l3 + b3[3]);
        *(float4*)&out[(size_t)(blockIdx.x * 256 + r2) * 4] =
            make_float4(e0, e1, e2, e3);
        s = e0 + e1 + e2 + e3;
    }
#pragma unroll
    for (int off = 1; off < 64; off <<= 1) s += __shfl_xor(s, off);
    if (lane == 0) bsum[wid] = s;
    __syncthreads();
    if (tid == 0) {
        float tot = 0.0f;
#pragma unroll
        for (int i = 0; i < 8; ++i) tot += bsum[i];
        atomicAdd(wsum, tot);
    }
}

__global__ __launch_bounds__(256)
void norm_kernel(float4* __restrict__ out, const float* __restrict__ wsum, int n4)
{
    const int i = blockIdx.x * 256 + threadIdx.x;
    if (i < n4) {
        const float inv = 1.0f / *wsum;
        float4 v = out[i];
        v.x *= inv; v.y *= inv; v.z *= inv; v.w *= inv;
        out[i] = v;
    }
}

extern "C" void kernel_launch(void* const* d_in, const int* in_sizes, int n_in,
                              void* d_out, int out_size, void* d_ws, size_t ws_size,
                              hipStream_t stream) {
    (void)in_sizes; (void)n_in; (void)ws_size;
    const float* x  = (const float*)d_in[0];
    const float* w1 = (const float*)d_in[1];
    const float* b1 = (const float*)d_in[2];
    const float* w2 = (const float*)d_in[3];
    const float* b2 = (const float*)d_in[4];
    const float* w3 = (const float*)d_in[5];
    const float* b3 = (const float*)d_in[6];
    float* out  = (float*)d_out;
    float* wsum = (float*)d_ws;

    hipMemsetAsync(wsum, 0, sizeof(float), stream);
    mlp_kernel<<<NBLOCKS, 512, 0, stream>>>(x, w1, b1, w2, b2, w3, b3, out, wsum);
    const int n4 = out_size >> 2;
    norm_kernel<<<(n4 + 255) / 256, 256, 0, stream>>>((float4*)out, wsum, n4);
}

// Round 2
// 216.754 us; speedup vs baseline: 1.0053x; 1.0053x over previous
//
#include <hip/hip_runtime.h>
#include <hip/hip_bf16.h>
#include <math.h>

// Fused MLP 256->64->16->4 + global softmax over flattened [B*4].
//
// Layer 1 via bf16 MFMA (16x16x32), 3-term split precision:
//   x*w ~= xh*wh + xl*wh + xh*wl   (xl*wl ~2^-18 dropped; verified R5 7.6e-6)
// R8 changes vs R7:
//  - no hipMemsetAsync / no atomic: each block stores its partial exp-sum to
//    ws[blockIdx.x]; norm_kernel reduces the 512 partials per-block.
//  - norm grid exact: 512x256 threads, one float4 each (was 4x over-sized
//    via out_size>>2 -> 16 MiB of extra traffic).
//  - s=0 x prefetch issued BEFORE w1 staging (first HBM miss hides under
//    staging work; __syncthreads drains vmcnt anyway so it's free).
//  - B-fragments (bh/bl) hoisted out of the mt loop (R6 shape): loaded once
//    per s-step, halves LDS read traffic vs R7.
// w1' staged per block in LDS [n][k] bf16 hi+lo, k-stride 520 (260dw%32==4
// -> conflict-free b128 reads). Epilogue reuses w1' LDS as h-stash
// (stride 68), layer-2/3 2 threads/row; __expf epilogue.

typedef __attribute__((ext_vector_type(8))) short bf16x8;  // 8 bf16 = 4 VGPRs
typedef __attribute__((ext_vector_type(4))) float f32x4;

#define WK 520
#define HS 68
#define NBLOCKS 512   // 131072 rows / 256 rows per block

__device__ __forceinline__ short f2bf(float v) {   // scalar fallback (staging)
    unsigned u = __float_as_uint(v);
    unsigned r = (u + 0x7FFFu + ((u >> 16) & 1u)) >> 16;
    return (short)r;
}
__device__ __forceinline__ float bf2f(short s) {
    return __uint_as_float(((unsigned)(unsigned short)s) << 16);
}

// 8 fp32 -> bf16 hi + lo fragments, packed converts
__device__ __forceinline__ void cvt8(const float4 v0, const float4 v1,
                                     bf16x8& ah, bf16x8& al)
{
    const float f[8] = {v0.x, v0.y, v0.z, v0.w, v1.x, v1.y, v1.z, v1.w};
    unsigned* ahp = (unsigned*)&ah;
    unsigned* alp = (unsigned*)&al;
#pragma unroll
    for (int p = 0; p < 4; ++p) {
        float2 fp = make_float2(f[2 * p], f[2 * p + 1]);
        __hip_bfloat162 h2 = __float22bfloat162_rn(fp);      // v_cvt_pk_bf16_f32
        float2 hf = __bfloat1622float2(h2);
        __hip_bfloat162 l2 =
            __float22bfloat162_rn(make_float2(fp.x - hf.x, fp.y - hf.y));
        union { __hip_bfloat162 b; unsigned u; } ch, cl;
        ch.b = h2; cl.b = l2;
        ahp[p] = ch.u;
        alp[p] = cl.u;
    }
}

__global__ __launch_bounds__(512, 4)
void mlp_kernel(const float* __restrict__ x, const float* __restrict__ w1,
                const float* __restrict__ b1, const float* __restrict__ w2,
                const float* __restrict__ b2, const float* __restrict__ w3,
                const float* __restrict__ b3, float* __restrict__ out,
                float* __restrict__ ws)
{
    // union: wlds = 64*520*2 = 66560 B; hs = 256*68*4 = 69632 B
    __shared__ __align__(16) char smem[256 * HS * 4];
    __shared__ float ws2[64 * 16];
    __shared__ float ws3[64];
    __shared__ float bs1[64];
    __shared__ float bsum[8];
    short* wlds = (short*)smem;
    float* hs   = (float*)smem;

    const int tid  = threadIdx.x;
    const int lane = tid & 63;
    const int wid  = tid >> 6;    // 0..7
    const int quad = lane >> 4;   // 0..3
    const int m16  = lane & 15;

    // ---- layer-1 x pointers + s=0 prefetch issued FIRST (hides under staging)
    const int row0 = blockIdx.x * 256 + wid * 32;
    const float* xb0 = x + (size_t)(row0 + m16) * 256 + quad * 8;
    const float* xb1 = xb0 + 16 * 256;

    float4 cur[4];
    cur[0] = *(const float4*)(xb0);
    cur[1] = *(const float4*)(xb0 + 4);
    cur[2] = *(const float4*)(xb1);
    cur[3] = *(const float4*)(xb1 + 4);

    // ---- stage small weights + w1 -> bf16 hi/lo in LDS ----
    for (int i = tid; i < 1024; i += 512) ws2[i] = w2[i];
    if (tid < 64) ws3[tid] = w3[tid];
    if (tid >= 64 && tid < 128) bs1[tid - 64] = b1[tid - 64];
    {
        const int n  = tid & 63;
        const int kb = (tid >> 6) * 4;
        for (int kk = kb; kk < 256; kk += 32) {
            const float v0 = w1[(size_t)(kk + 0) * 64 + n];
            const float v1 = w1[(size_t)(kk + 1) * 64 + n];
            const float v2 = w1[(size_t)(kk + 2) * 64 + n];
            const float v3 = w1[(size_t)(kk + 3) * 64 + n];
            short4 hi, lo;
            hi.x = f2bf(v0); lo.x = f2bf(v0 - bf2f(hi.x));
            hi.y = f2bf(v1); lo.y = f2bf(v1 - bf2f(hi.y));
            hi.z = f2bf(v2); lo.z = f2bf(v2 - bf2f(hi.z));
            hi.w = f2bf(v3); lo.w = f2bf(v3 - bf2f(hi.w));
            *(short4*)&wlds[n * WK + kk]       = hi;   // hi at k
            *(short4*)&wlds[n * WK + 256 + kk] = lo;   // lo at 256 + k
        }
    }
    __syncthreads();

    // ---- layer 1 MFMA: wave = 32 rows x 64 cols ----
    f32x4 acc[2][4];
#pragma unroll
    for (int mt = 0; mt < 2; ++mt)
#pragma unroll
        for (int t = 0; t < 4; ++t) acc[mt][t] = (f32x4)0.0f;

#pragma unroll
    for (int s = 0; s < 8; ++s) {
        float4 nxt[4];
        if (s < 7) {           // issue next-step loads FIRST (latency hiding)
            const int off = (s + 1) * 32;
            nxt[0] = *(const float4*)(xb0 + off);
            nxt[1] = *(const float4*)(xb0 + off + 4);
            nxt[2] = *(const float4*)(xb1 + off);
            nxt[3] = *(const float4*)(xb1 + off + 4);
        }
        bf16x8 bh[4], bl[4];
#pragma unroll
        for (int t = 0; t < 4; ++t) {  // B-frag: n = t*16+m16, k = quad*8+j
            const short* bp = &wlds[(t * 16 + m16) * WK + s * 32 + quad * 8];
            bh[t] = *(const bf16x8*)bp;
            bl[t] = *(const bf16x8*)(bp + 256);
        }
#pragma unroll
        for (int mt = 0; mt < 2; ++mt) {
            bf16x8 ah, al;
            cvt8(cur[mt * 2 + 0], cur[mt * 2 + 1], ah, al);
            // 3-term split: ah*bh + al*bh + ah*bl
#pragma unroll
            for (int t = 0; t < 4; ++t)
                acc[mt][t] = __builtin_amdgcn_mfma_f32_16x16x32_bf16(
                    ah, bh[t], acc[mt][t], 0, 0, 0);
#pragma unroll
            for (int t = 0; t < 4; ++t)
                acc[mt][t] = __builtin_amdgcn_mfma_f32_16x16x32_bf16(
                    al, bh[t], acc[mt][t], 0, 0, 0);
#pragma unroll
            for (int t = 0; t < 4; ++t)
                acc[mt][t] = __builtin_amdgcn_mfma_f32_16x16x32_bf16(
                    ah, bl[t], acc[mt][t], 0, 0, 0);
        }
#pragma unroll
        for (int i = 0; i < 4; ++i) cur[i] = nxt[i];
    }
    __syncthreads();   // all waves done reading wlds -> reuse as hs

    // ---- bias + relu -> h stash (C/D: col = t*16+m16, row = quad*4+r) ----
#pragma unroll
    for (int mt = 0; mt < 2; ++mt)
#pragma unroll
        for (int t = 0; t < 4; ++t) {
            const float bc = bs1[t * 16 + m16];
#pragma unroll
            for (int r = 0; r < 4; ++r) {
                const int rr = wid * 32 + mt * 16 + quad * 4 + r;
                hs[rr * HS + t * 16 + m16] = fmaxf(acc[mt][t][r] + bc, 0.0f);
            }
        }
    __syncthreads();

    // ---- layers 2/3: 2 threads per row, 8 z2-cols each ----
    const int r2 = tid >> 1;
    const int jq = (tid & 1) * 8;
    float z2[8];
#pragma unroll
    for (int jj = 0; jj < 8; ++jj) z2[jj] = b2[jq + jj];
#pragma unroll 4
    for (int c = 0; c < 64; c += 4) {
        const float4 h4 = *(const float4*)&hs[r2 * HS + c];
        const float hv[4] = {h4.x, h4.y, h4.z, h4.w};
#pragma unroll
        for (int i = 0; i < 4; ++i)
#pragma unroll
            for (int jj = 0; jj < 8; ++jj)
                z2[jj] = fmaf(hv[i], ws2[(c + i) * 16 + jq + jj], z2[jj]);
    }
    float l0 = 0.f, l1 = 0.f, l2 = 0.f, l3 = 0.f;
#pragma unroll
    for (int jj = 0; jj < 8; ++jj) {
        const float th = tanhf(z2[jj]);
        const int j = jq + jj;
        l0 = fmaf(th, ws3[j * 4 + 0], l0);
        l1 = fmaf(th, ws3[j * 4 + 1], l1);
        l2 = fmaf(th, ws3[j * 4 + 2], l2);
        l3 = fmaf(th, ws3[j * 4 + 3], l3);
    }
    l0 += __shfl_xor(l0, 1); l1 += __shfl_xor(l1, 1);
    l2 += __shfl_xor(l2, 1); l3 += __shfl_xor(l3, 1);

    float s = 0.0f;
    if ((tid & 1) == 0) {
        const float e0 = __expf(l0 + b3[0]);
        const float e1 = __expf(l1 + b3[1]);
        const float e2 = __expf(l2 + b3[2]);
        const float e3 = __expf(l3 + b3[3]);
        *(float4*)&out[(size_t)(blockIdx.x * 256 + r2) * 4] =
            make_float4(e0, e1, e2, e3);
        s = e0 + e1 + e2 + e3;
    }
#pragma unroll
    for (int off = 1; off < 64; off <<= 1) s += __shfl_xor(s, off);
    if (lane == 0) bsum[wid] = s;
    __syncthreads();
    if (tid == 0) {
        float tot = 0.0f;
#pragma unroll
        for (int i = 0; i < 8; ++i) tot += bsum[i];
        ws[blockIdx.x] = tot;     // per-block partial, no atomic, no memset
    }
}

// 512 blocks x 256 threads: each block reduces the 512 partials, then each
// thread scales exactly one float4 of out (131072 total, exact grid).
__global__ __launch_bounds__(256)
void norm_kernel(float4* __restrict__ out, const float* __restrict__ ws)
{
    __shared__ float red[4];
    const int tid = threadIdx.x;

    float s = ws[tid] + ws[tid + 256];
#pragma unroll
    for (int off = 1; off < 64; off <<= 1) s += __shfl_xor(s, off);
    if ((tid & 63) == 0) red[tid >> 6] = s;
    __syncthreads();
    const float inv = 1.0f / (red[0] + red[1] + red[2] + red[3]);

    const int i = blockIdx.x * 256 + tid;
    float4 v = out[i];
    v.x *= inv; v.y *= inv; v.z *= inv; v.w *= inv;
    out[i] = v;
}

extern "C" void kernel_launch(void* const* d_in, const int* in_sizes, int n_in,
                              void* d_out, int out_size, void* d_ws, size_t ws_size,
                              hipStream_t stream) {
    (void)in_sizes; (void)n_in; (void)ws_size; (void)out_size;
    const float* x  = (const float*)d_in[0];
    const float* w1 = (const float*)d_in[1];
    const float* b1 = (const float*)d_in[2];
    const float* w2 = (const float*)d_in[3];
    const float* b2 = (const float*)d_in[4];
    const float* w3 = (const float*)d_in[5];
    const float* b3 = (const float*)d_in[6];
    float* out = (float*)d_out;
    float* ws  = (float*)d_ws;

    mlp_kernel<<<NBLOCKS, 512, 0, stream>>>(x, w1, b1, w2, b2, w3, b3, out, ws);
    norm_kernel<<<NBLOCKS, 256, 0, stream>>>((float4*)out, ws);
}